// Round 8
// baseline (537.285 us; speedup 1.0000x reference)
//
#include <hip/hip_runtime.h>

#define SB 16
#define SN 2048
#define SD 128
#define NM 2049
#define SZ (SB*SN*SD)   // elements per (B,N,D) tensor

typedef __bf16 bf16x8 __attribute__((ext_vector_type(8)));
typedef float f32x4 __attribute__((ext_vector_type(4)));

// float -> bf16 round-to-nearest-even (inputs are finite)
__device__ __forceinline__ unsigned short f2b(float f){
  union { float f; unsigned int u; } v; v.f = f;
  unsigned int r = v.u + 0x7fffu + ((v.u >> 16) & 1u);
  return (unsigned short)(r >> 16);
}

__device__ __forceinline__ void async16(const void* g, void* l){
  __builtin_amdgcn_global_load_lds(
      (__attribute__((address_space(1))) void*)(g),
      (__attribute__((address_space(3))) void*)(l), 16, 0, 0);
}

// ---- transpose + cvt the 4 weight matrices: Wt[n*128+k] = bf16(W[k*128+n]) ----
__global__ __launch_bounds__(256) void prep_w_kernel(
    const float* __restrict__ Wq, const float* __restrict__ Wk,
    const float* __restrict__ Wv, const float* __restrict__ Wo,
    unsigned short* __restrict__ out)
{
  int widx = blockIdx.x >> 4;
  int kg   = blockIdx.x & 15;
  const float* W = (widx==0)?Wq:(widx==1)?Wk:(widx==2)?Wv:Wo;
  unsigned short* O = out + widx*16384;
  int t = threadIdx.x;
  int k = kg*8 + (t>>5);
  int n = (t&31)*4;
  float4 v = *reinterpret_cast<const float4*>(W + k*SD + n);
  O[(n+0)*SD + k] = f2b(v.x);
  O[(n+1)*SD + k] = f2b(v.y);
  O[(n+2)*SD + k] = f2b(v.z);
  O[(n+3)*SD + k] = f2b(v.w);
}

// ---- fused projection weight: Wkv = Wk@Wv (f32), bkv = bk@Wv + bv.
// WkvT (bf16, transposed like the others) overwrites the (unused) WvT slot.
__global__ __launch_bounds__(256) void prep_wkv_kernel(
    const float* __restrict__ Wk, const float* __restrict__ Wv,
    const float* __restrict__ bk, const float* __restrict__ bv,
    unsigned short* __restrict__ WkvT, float* __restrict__ bkv)
{
  int t = threadIdx.x;
  int k = blockIdx.x*8 + (t>>5);
  int n0 = (t&31)*4;
  float ax=0.f, ay=0.f, az=0.f, aw=0.f;
  for (int m=0;m<SD;m++){
    float wk = Wk[k*SD+m];
    float4 wv = *reinterpret_cast<const float4*>(Wv + m*SD + n0);
    ax += wk*wv.x; ay += wk*wv.y; az += wk*wv.z; aw += wk*wv.w;
  }
  WkvT[(n0+0)*SD + k] = f2b(ax);
  WkvT[(n0+1)*SD + k] = f2b(ay);
  WkvT[(n0+2)*SD + k] = f2b(az);
  WkvT[(n0+3)*SD + k] = f2b(aw);
  if (blockIdx.x==0 && t < SD){
    float a = 0.f;
    for (int m=0;m<SD;m++) a += bk[m]*Wv[m*SD + t];
    bkv[t] = a + bv[t];
  }
}

// ---- q/k/v projections + mask byte-packing, one grid (2048 blocks).
// blocks [0,1024): GEMM role, parity split (round-6 passing form):
//   even: kv-block; odd: q-block. Outputs staged through per-wave LDS strips
//   for fully coalesced row writes.
// blocks [1024,2048): pack role — pure streaming cast-copy, NO cross-lane ops:
//   pmask8[b*2048+q][k] = (mask[b][1+q][1+k] != 0). 268MB int32 -> 67MB bytes.
//   Kills the 1.5x misalignment amplification once; flash then reads 4x fewer
//   mask bytes. Overlaps the GEMM blocks on the same dispatch.
__global__ __launch_bounds__(256,4) void qkv_kernel(
    const float* __restrict__ query, const float* __restrict__ key,
    const int* __restrict__ mask,
    const unsigned short* __restrict__ wts,
    const float* __restrict__ bq, const float* __restrict__ bk,
    const float* __restrict__ bkv,
    unsigned short* __restrict__ qb, unsigned short* __restrict__ kb,
    unsigned short* __restrict__ vt, unsigned char* __restrict__ pmask8)
{
  __shared__ unsigned short vT[128*72];     // [d][64 cols], stride 72
  __shared__ unsigned short kq[4][16*136];  // per-wave output strip

  int tid=threadIdx.x;
  int w=tid>>6, ln=tid&63, g=ln>>4, lm=ln&15;
  int bi = blockIdx.x;

  if (bi >= 1024){
    // ---------------- pack role ----------------
    int pid = bi - 1024;                  // 0..1023, 32 rows each
    for (int rr=0; rr<8; rr++){
      int row = pid*32 + w*8 + rr;        // 0..32767 = b*2048 + qrow
      int b = row >> 11, qr = row & 2047;
      const int* src = mask + (size_t)b*NM*NM + (size_t)(1+qr)*NM + 1;
      unsigned char* dst = pmask8 + (size_t)row*2048;
      for (int j=0;j<8;j++){
        int c = j*256 + ln*4;
        unsigned int pv =  (src[c+0]?1u:0u)
                        | ((src[c+1]?1u:0u)<<8)
                        | ((src[c+2]?1u:0u)<<16)
                        | ((src[c+3]?1u:0u)<<24);
        *reinterpret_cast<unsigned int*>(dst + c) = pv;
      }
    }
    return;
  }

  int id = bi >> 1;                      // 0..511
  int b = id >> 5, nt = id & 31;
  size_t rowbase = (size_t)b*SN + nt*64 + w*16;
  unsigned short* st = &kq[w][0];
  int srow = ln>>2, sqtr = ln&3;         // strip readback: row 0..15, quarter 0..3

  if ((bi & 1) == 0){
    // ---------------- kv-block ----------------
    const unsigned short* WkT  = wts + 16384;
    const unsigned short* WkvT = wts + 32768;
    const float* xr = key + (rowbase + lm)*SD;
    bf16x8 af[4];
    for (int ks=0;ks<4;ks++){
      float4 x0 = *reinterpret_cast<const float4*>(xr + ks*32 + g*8);
      float4 x1 = *reinterpret_cast<const float4*>(xr + ks*32 + g*8 + 4);
      union { bf16x8 v; unsigned short s[8]; } u;
      u.s[0]=f2b(x0.x); u.s[1]=f2b(x0.y); u.s[2]=f2b(x0.z); u.s[3]=f2b(x0.w);
      u.s[4]=f2b(x1.x); u.s[5]=f2b(x1.y); u.s[6]=f2b(x1.z); u.s[7]=f2b(x1.w);
      af[ks]=u.v;
    }
    // k = key@Wk + bk  -> strip -> coalesced
    for (int d=0; d<8; d++){
      f32x4 acc = {0.f,0.f,0.f,0.f};
      for (int ks=0;ks<4;ks++){
        bf16x8 wf = *reinterpret_cast<const bf16x8*>(WkT + (d*16+lm)*SD + ks*32 + g*8);
        acc = __builtin_amdgcn_mfma_f32_16x16x32_bf16(af[ks], wf, acc, 0,0,0);
      }
      float bb = bk[d*16+lm];
      for (int r=0;r<4;r++)
        st[(4*g+r)*136 + d*16 + lm] = f2b(acc[r]+bb);
    }
    asm volatile("" ::: "memory");
    {
      const uint4* s4 = reinterpret_cast<const uint4*>(&st[srow*136 + sqtr*32]);
      uint4* d4 = reinterpret_cast<uint4*>(kb + (rowbase + srow)*SD + sqtr*32);
      d4[0]=s4[0]; d4[1]=s4[1]; d4[2]=s4[2]; d4[3]=s4[3];
    }
    // v^T = Wkv^T @ key^T + bkv  (C: row=d-local 4g+r, col=key n-local lm)
    for (int d=0; d<8; d++){
      f32x4 acc = {0.f,0.f,0.f,0.f};
      for (int ks=0;ks<4;ks++){
        bf16x8 wf = *reinterpret_cast<const bf16x8*>(WkvT + (d*16+lm)*SD + ks*32 + g*8);
        acc = __builtin_amdgcn_mfma_f32_16x16x32_bf16(wf, af[ks], acc, 0,0,0);
      }
      float4 bb = *reinterpret_cast<const float4*>(bkv + d*16 + 4*g);
      vT[(d*16 + 4*g + 0)*72 + w*16 + lm] = f2b(acc[0]+bb.x);
      vT[(d*16 + 4*g + 1)*72 + w*16 + lm] = f2b(acc[1]+bb.y);
      vT[(d*16 + 4*g + 2)*72 + w*16 + lm] = f2b(acc[2]+bb.z);
      vT[(d*16 + 4*g + 3)*72 + w*16 + lm] = f2b(acc[3]+bb.w);
    }
    __syncthreads();
    // coalesced write: 128 rows x 64 cols; thread t handles half a row
    int d = tid>>1, half = tid&1;
    const uint4* src4 = reinterpret_cast<const uint4*>(&vT[d*72 + half*32]);
    uint4* dst4 = reinterpret_cast<uint4*>(vt + (size_t)b*SD*SN + (size_t)d*SN + nt*64 + half*32);
    dst4[0]=src4[0]; dst4[1]=src4[1]; dst4[2]=src4[2]; dst4[3]=src4[3];
  } else {
    // ---------------- q-block ----------------
    const unsigned short* WqT = wts;
    const float sc = 0.08838834764831845f;  // 1/sqrt(128)
    const float* xr = query + (rowbase + lm)*SD;
    bf16x8 af[4];
    for (int ks=0;ks<4;ks++){
      float4 x0 = *reinterpret_cast<const float4*>(xr + ks*32 + g*8);
      float4 x1 = *reinterpret_cast<const float4*>(xr + ks*32 + g*8 + 4);
      union { bf16x8 v; unsigned short s[8]; } u;
      u.s[0]=f2b(x0.x); u.s[1]=f2b(x0.y); u.s[2]=f2b(x0.z); u.s[3]=f2b(x0.w);
      u.s[4]=f2b(x1.x); u.s[5]=f2b(x1.y); u.s[6]=f2b(x1.z); u.s[7]=f2b(x1.w);
      af[ks]=u.v;
    }
    for (int d=0; d<8; d++){
      f32x4 acc = {0.f,0.f,0.f,0.f};
      for (int ks=0;ks<4;ks++){
        bf16x8 wf = *reinterpret_cast<const bf16x8*>(WqT + (d*16+lm)*SD + ks*32 + g*8);
        acc = __builtin_amdgcn_mfma_f32_16x16x32_bf16(af[ks], wf, acc, 0,0,0);
      }
      float bb = bq[d*16+lm];
      for (int r=0;r<4;r++)
        st[(4*g+r)*136 + d*16 + lm] = f2b((acc[r]+bb)*sc);
    }
    asm volatile("" ::: "memory");
    {
      const uint4* s4 = reinterpret_cast<const uint4*>(&st[srow*136 + sqtr*32]);
      uint4* d4 = reinterpret_cast<uint4*>(qb + (rowbase + srow)*SD + sqtr*32);
      d4[0]=s4[0]; d4[1]=s4[1]; d4[2]=s4[2]; d4[3]=s4[3];
    }
  }
}

// ---- flash attention + fused output projection ----
// Proven round-1 structure verbatim (512 blocks, 4 waves, 64 q-rows, 2/CU);
// only change: mask comes from pmask8 bytes (4x fewer bytes, aligned rows,
// plain loads so the L1 line fetched at tile kt serves kt+1).
__global__ __launch_bounds__(256,4) void flash_kernel(
    const unsigned short* __restrict__ qb, const unsigned short* __restrict__ kb,
    const unsigned short* __restrict__ vt, const unsigned char* __restrict__ pmask8,
    const unsigned short* __restrict__ WoT, const float* __restrict__ bo,
    float* __restrict__ out)
{
  __shared__ unsigned short bufK[2][64*128];   // [key][d], chunk-swizzled
  __shared__ unsigned short bufV[2][128*64];   // [d][key], chunk-swizzled
  __shared__ unsigned short ldsP[4*16*72];     // per-wave P strip

  int tid=threadIdx.x;
  int w=tid>>6, ln=tid&63, g=ln>>4, lm=ln&15;
  int xcd   = blockIdx.x & 7;
  int inner = blockIdx.x >> 3;            // 0..63
  int b  = xcd*2 + (inner>>5);
  int qt = inner & 31;
  int q0 = qt*64;

  const unsigned short* Qb = qb + (size_t)b*SN*SD;
  const unsigned short* Kb = kb + (size_t)b*SN*SD;
  const unsigned short* Vb = vt + (size_t)b*SD*SN;

  auto issueK = [&](int k0, int bi){
    const char* gbase = (const char*)Kb + (size_t)k0*256;
    for (int c=0;c<4;c++){
      int p = c*256 + tid;
      int row = p>>4, lc = (p&15) ^ (row&15);
      async16(gbase + (size_t)row*256 + lc*16, (char*)bufK[bi] + p*16);
    }
  };
  auto issueV = [&](int k0, int bi){
    const char* gbase = (const char*)Vb + (size_t)k0*2;
    for (int c=0;c<4;c++){
      int p = c*256 + tid;
      int row = p>>3, lc = (p&7) ^ (row&7);
      async16(gbase + (size_t)row*4096 + lc*16, (char*)bufV[bi] + p*16);
    }
  };

  issueK(0,0); issueV(0,0);

  bf16x8 qf[4];
  {
    const unsigned short* qr = Qb + (size_t)(q0 + w*16 + lm)*SD;
    for (int ks=0;ks<4;ks++)
      qf[ks] = *reinterpret_cast<const bf16x8*>(qr + ks*32 + g*8);
  }

  // packed byte mask: row r's byte for tile kt, chunk ct is pmb[r*2048 + kt*64 + ct*16]
  const unsigned char* pmb = pmask8 + ((size_t)(b*2048 + q0 + w*16 + 4*g))*2048 + lm;
  int mreg[16];
  for (int ct=0;ct<4;ct++)
    for (int r=0;r<4;r++)
      mreg[ct*4+r] = pmb[r*2048 + ct*16];

  float mrow[4], lrow[4], al[4];
  f32x4 acc[8];
  for (int r=0;r<4;r++){ mrow[r]=-INFINITY; lrow[r]=0.f; }
  for (int d=0;d<8;d++){ f32x4 z={0.f,0.f,0.f,0.f}; acc[d]=z; }
  unsigned short* pw = &ldsP[w*16*72];

  for (int kt=0; kt<32; kt++){
    __syncthreads();          // DMA for buf[kt&1] drained; all done reading buf[(kt+1)&1]
    int cur = kt&1;
    if (kt<31){ issueK((kt+1)*64, cur^1); issueV((kt+1)*64, cur^1); }

    // ---- S = Q K^T (wave strip: 16 q-rows x 64 keys), swizzled reads ----
    f32x4 s[4];
    __builtin_amdgcn_s_setprio(1);
    for (int ct=0;ct<4;ct++){
      f32x4 z = {0.f,0.f,0.f,0.f};
      for (int ks=0;ks<4;ks++){
        bf16x8 kf = *reinterpret_cast<const bf16x8*>(
            &bufK[cur][(ct*16+lm)*128 + (((ks*4+g)^lm))*8]);
        z = __builtin_amdgcn_mfma_f32_16x16x32_bf16(qf[ks], kf, z, 0,0,0);
      }
      s[ct]=z;
    }
    __builtin_amdgcn_s_setprio(0);

    // apply mask bytes, then prefetch next tile's bytes
    for (int ct=0;ct<4;ct++)
      for (int r=0;r<4;r++)
        s[ct][r] = mreg[ct*4+r] ? -INFINITY : s[ct][r];
    if (kt<31){
      const unsigned char* mp = pmb + (kt+1)*64;
      for (int ct=0;ct<4;ct++)
        for (int r=0;r<4;r++)
          mreg[ct*4+r] = mp[r*2048 + ct*16];
    }

    // ---- online softmax ----
    for (int r=0;r<4;r++){
      float v = fmaxf(fmaxf(s[0][r],s[1][r]), fmaxf(s[2][r],s[3][r]));
      v = fmaxf(v, __shfl_xor(v,1,16));
      v = fmaxf(v, __shfl_xor(v,2,16));
      v = fmaxf(v, __shfl_xor(v,4,16));
      v = fmaxf(v, __shfl_xor(v,8,16));
      float mn = fmaxf(mrow[r], v);
      bool dead = (mn == -INFINITY);    // fully-masked so far -> zeros (NaN->0 semantics)
      float a = dead ? 1.f : __expf(mrow[r]-mn);
      float rsum = 0.f;
      for (int ct=0;ct<4;ct++){
        float p = dead ? 0.f : __expf(s[ct][r]-mn);
        s[ct][r]=p; rsum += p;
      }
      rsum += __shfl_xor(rsum,1,16);
      rsum += __shfl_xor(rsum,2,16);
      rsum += __shfl_xor(rsum,4,16);
      rsum += __shfl_xor(rsum,8,16);
      lrow[r] = lrow[r]*a + rsum;
      mrow[r] = mn;
      al[r] = a;
    }
    for (int d=0;d<8;d++)
      for (int r=0;r<4;r++)
        acc[d][r] *= al[r];

    // P: C-layout -> per-wave LDS strip -> A-frags
    for (int ct=0;ct<4;ct++){
      int col = ct*16+lm;
      for (int r=0;r<4;r++)
        pw[(4*g+r)*72 + col] = f2b(s[ct][r]);
    }
    asm volatile("" ::: "memory");
    bf16x8 pa0 = *reinterpret_cast<const bf16x8*>(&pw[lm*72 + g*8]);
    bf16x8 pa1 = *reinterpret_cast<const bf16x8*>(&pw[lm*72 + 32 + g*8]);
    asm volatile("" ::: "memory");

    // O += P V (swizzled V reads)
    __builtin_amdgcn_s_setprio(1);
    for (int d=0;d<8;d++){
      bf16x8 v0 = *reinterpret_cast<const bf16x8*>(
          &bufV[cur][(d*16+lm)*64 + ((g^(lm&7)))*8]);
      acc[d] = __builtin_amdgcn_mfma_f32_16x16x32_bf16(pa0, v0, acc[d], 0,0,0);
      bf16x8 v1 = *reinterpret_cast<const bf16x8*>(
          &bufV[cur][(d*16+lm)*64 + (((4+g)^(lm&7)))*8]);
      acc[d] = __builtin_amdgcn_mfma_f32_16x16x32_bf16(pa1, v1, acc[d], 0,0,0);
    }
    __builtin_amdgcn_s_setprio(0);
  }

  // ---- epilogue: out = (O/l) @ Wo + bo ----
  __syncthreads();            // done with bufK/bufV; reuse as bf16 A-frag strips
  float inv[4];
  for (int r=0;r<4;r++) inv[r] = (lrow[r] > 0.f) ? (1.f/lrow[r]) : 0.f;
  unsigned short* strip = &bufK[0][0] + w*2176;   // 16 rows x 136 stride
  for (int d=0;d<8;d++)
    for (int r=0;r<4;r++)
      strip[(4*g+r)*136 + d*16 + lm] = f2b(acc[d][r]*inv[r]);
  asm volatile("" ::: "memory");
  bf16x8 oa[4];
  for (int ks=0;ks<4;ks++)
    oa[ks] = *reinterpret_cast<const bf16x8*>(&strip[lm*136 + ks*32 + g*8]);
  asm volatile("" ::: "memory");
  float* Ob = out + ((size_t)b*SN + q0 + w*16)*SD;
  for (int dc=0; dc<8; dc++){
    f32x4 o = {0.f,0.f,0.f,0.f};
    for (int ks=0;ks<4;ks++){
      bf16x8 wf = *reinterpret_cast<const bf16x8*>(WoT + (dc*16+lm)*SD + ks*32 + g*8);
      o = __builtin_amdgcn_mfma_f32_16x16x32_bf16(oa[ks], wf, o, 0,0,0);
    }
    float bb = bo[dc*16+lm];
    for (int r=0;r<4;r++)
      __builtin_nontemporal_store(o[r]+bb, &Ob[(size_t)(4*g+r)*SD + dc*16 + lm]);
  }
}

extern "C" void kernel_launch(void* const* d_in, const int* in_sizes, int n_in,
                              void* d_out, int out_size, void* d_ws, size_t ws_size,
                              hipStream_t stream)
{
  const float* query = (const float*)d_in[0];
  const float* key   = (const float*)d_in[1];
  const int*   mask  = (const int*)d_in[2];
  const float* Wq = (const float*)d_in[3];
  const float* bq = (const float*)d_in[4];
  const float* Wk = (const float*)d_in[5];
  const float* bk = (const float*)d_in[6];
  const float* Wv = (const float*)d_in[7];
  const float* bv = (const float*)d_in[8];
  const float* Wo = (const float*)d_in[9];
  const float* bo = (const float*)d_in[10];
  float* out = (float*)d_out;

  // workspace: qb, kb, vt (bf16) + transposed weights + fused bias + byte mask
  unsigned short* qb = (unsigned short*)d_ws;
  unsigned short* kb = qb + SZ;
  unsigned short* vt = kb + SZ;
  unsigned short* wts = vt + SZ;            // WqT | WkT | WkvT(overwrites WvT) | WoT
  float* bkv = (float*)(wts + 65536);       // 128 f32
  unsigned char* pmask8 = (unsigned char*)(bkv + 128);  // [16*2048][2048] = 67MB

  prep_w_kernel  <<<64,256,0,stream>>>(Wq,Wk,Wv,Wo,wts);
  prep_wkv_kernel<<<16,256,0,stream>>>(Wk,Wv,bk,bv, wts+32768, bkv);
  qkv_kernel     <<<2048,256,0,stream>>>(query, key, mask, wts, bq, bk, bkv,
                                         qb, kb, vt, pmask8);
  flash_kernel   <<<512,256,0,stream>>>(qb, kb, vt, pmask8, wts+49152, bo, out);
}

// Round 9
// 493.721 us; speedup vs baseline: 1.0882x; 1.0882x over previous
//
#include <hip/hip_runtime.h>

#define SB 16
#define SN 2048
#define SD 128
#define NM 2049
#define SZ (SB*SN*SD)   // elements per (B,N,D) tensor

typedef __bf16 bf16x8 __attribute__((ext_vector_type(8)));
typedef float f32x4 __attribute__((ext_vector_type(4)));

// float -> bf16 round-to-nearest-even (inputs are finite)
__device__ __forceinline__ unsigned short f2b(float f){
  union { float f; unsigned int u; } v; v.f = f;
  unsigned int r = v.u + 0x7fffu + ((v.u >> 16) & 1u);
  return (unsigned short)(r >> 16);
}

__device__ __forceinline__ void async16(const void* g, void* l){
  __builtin_amdgcn_global_load_lds(
      (__attribute__((address_space(1))) void*)(g),
      (__attribute__((address_space(3))) void*)(l), 16, 0, 0);
}

// ---- transpose + cvt the 4 weight matrices: Wt[n*128+k] = bf16(W[k*128+n]) ----
__global__ __launch_bounds__(256) void prep_w_kernel(
    const float* __restrict__ Wq, const float* __restrict__ Wk,
    const float* __restrict__ Wv, const float* __restrict__ Wo,
    unsigned short* __restrict__ out)
{
  int widx = blockIdx.x >> 4;
  int kg   = blockIdx.x & 15;
  const float* W = (widx==0)?Wq:(widx==1)?Wk:(widx==2)?Wv:Wo;
  unsigned short* O = out + widx*16384;
  int t = threadIdx.x;
  int k = kg*8 + (t>>5);
  int n = (t&31)*4;
  float4 v = *reinterpret_cast<const float4*>(W + k*SD + n);
  O[(n+0)*SD + k] = f2b(v.x);
  O[(n+1)*SD + k] = f2b(v.y);
  O[(n+2)*SD + k] = f2b(v.z);
  O[(n+3)*SD + k] = f2b(v.w);
}

// ---- fused projection weight: Wkv = Wk@Wv (f32), bkv = bk@Wv + bv.
// WkvT (bf16, transposed like the others) overwrites the (unused) WvT slot.
__global__ __launch_bounds__(256) void prep_wkv_kernel(
    const float* __restrict__ Wk, const float* __restrict__ Wv,
    const float* __restrict__ bk, const float* __restrict__ bv,
    unsigned short* __restrict__ WkvT, float* __restrict__ bkv)
{
  int t = threadIdx.x;
  int k = blockIdx.x*8 + (t>>5);
  int n0 = (t&31)*4;
  float ax=0.f, ay=0.f, az=0.f, aw=0.f;
  for (int m=0;m<SD;m++){
    float wk = Wk[k*SD+m];
    float4 wv = *reinterpret_cast<const float4*>(Wv + m*SD + n0);
    ax += wk*wv.x; ay += wk*wv.y; az += wk*wv.z; aw += wk*wv.w;
  }
  WkvT[(n0+0)*SD + k] = f2b(ax);
  WkvT[(n0+1)*SD + k] = f2b(ay);
  WkvT[(n0+2)*SD + k] = f2b(az);
  WkvT[(n0+3)*SD + k] = f2b(aw);
  if (blockIdx.x==0 && t < SD){
    float a = 0.f;
    for (int m=0;m<SD;m++) a += bk[m]*Wv[m*SD + t];
    bkv[t] = a + bv[t];
  }
}

// ---- q/k/v projections. 1024 blocks, parity split (round-6/8 passing form):
//   even: kv-block — k = key@Wk+bk and v^T = Wkv^T@key^T+bkv; both staged
//         through LDS and written fully coalesced (64B/lane rows).
//   odd:  q-block — q = (query@Wq+bq)/sqrt(D), same LDS-strip store path.
__global__ __launch_bounds__(256,4) void qkv_kernel(
    const float* __restrict__ query, const float* __restrict__ key,
    const unsigned short* __restrict__ wts,
    const float* __restrict__ bq, const float* __restrict__ bk,
    const float* __restrict__ bkv,
    unsigned short* __restrict__ qb, unsigned short* __restrict__ kb,
    unsigned short* __restrict__ vt)
{
  __shared__ unsigned short vT[128*72];     // [d][64 cols], stride 72
  __shared__ unsigned short kq[4][16*136];  // per-wave output strip

  int tid=threadIdx.x;
  int w=tid>>6, ln=tid&63, g=ln>>4, lm=ln&15;
  int bi = blockIdx.x;

  int id = bi >> 1;                      // 0..511
  int b = id >> 5, nt = id & 31;
  size_t rowbase = (size_t)b*SN + nt*64 + w*16;
  unsigned short* st = &kq[w][0];
  int srow = ln>>2, sqtr = ln&3;         // strip readback: row 0..15, quarter 0..3

  if ((bi & 1) == 0){
    // ---------------- kv-block ----------------
    const unsigned short* WkT  = wts + 16384;
    const unsigned short* WkvT = wts + 32768;
    const float* xr = key + (rowbase + lm)*SD;
    bf16x8 af[4];
    for (int ks=0;ks<4;ks++){
      float4 x0 = *reinterpret_cast<const float4*>(xr + ks*32 + g*8);
      float4 x1 = *reinterpret_cast<const float4*>(xr + ks*32 + g*8 + 4);
      union { bf16x8 v; unsigned short s[8]; } u;
      u.s[0]=f2b(x0.x); u.s[1]=f2b(x0.y); u.s[2]=f2b(x0.z); u.s[3]=f2b(x0.w);
      u.s[4]=f2b(x1.x); u.s[5]=f2b(x1.y); u.s[6]=f2b(x1.z); u.s[7]=f2b(x1.w);
      af[ks]=u.v;
    }
    // k = key@Wk + bk  -> strip -> coalesced
    for (int d=0; d<8; d++){
      f32x4 acc = {0.f,0.f,0.f,0.f};
      for (int ks=0;ks<4;ks++){
        bf16x8 wf = *reinterpret_cast<const bf16x8*>(WkT + (d*16+lm)*SD + ks*32 + g*8);
        acc = __builtin_amdgcn_mfma_f32_16x16x32_bf16(af[ks], wf, acc, 0,0,0);
      }
      float bb = bk[d*16+lm];
      for (int r=0;r<4;r++)
        st[(4*g+r)*136 + d*16 + lm] = f2b(acc[r]+bb);
    }
    asm volatile("" ::: "memory");
    {
      const uint4* s4 = reinterpret_cast<const uint4*>(&st[srow*136 + sqtr*32]);
      uint4* d4 = reinterpret_cast<uint4*>(kb + (rowbase + srow)*SD + sqtr*32);
      d4[0]=s4[0]; d4[1]=s4[1]; d4[2]=s4[2]; d4[3]=s4[3];
    }
    // v^T = Wkv^T @ key^T + bkv  (C: row=d-local 4g+r, col=key n-local lm)
    for (int d=0; d<8; d++){
      f32x4 acc = {0.f,0.f,0.f,0.f};
      for (int ks=0;ks<4;ks++){
        bf16x8 wf = *reinterpret_cast<const bf16x8*>(WkvT + (d*16+lm)*SD + ks*32 + g*8);
        acc = __builtin_amdgcn_mfma_f32_16x16x32_bf16(wf, af[ks], acc, 0,0,0);
      }
      float4 bb = *reinterpret_cast<const float4*>(bkv + d*16 + 4*g);
      vT[(d*16 + 4*g + 0)*72 + w*16 + lm] = f2b(acc[0]+bb.x);
      vT[(d*16 + 4*g + 1)*72 + w*16 + lm] = f2b(acc[1]+bb.y);
      vT[(d*16 + 4*g + 2)*72 + w*16 + lm] = f2b(acc[2]+bb.z);
      vT[(d*16 + 4*g + 3)*72 + w*16 + lm] = f2b(acc[3]+bb.w);
    }
    __syncthreads();
    // coalesced write: 128 rows x 64 cols; thread t handles half a row
    int d = tid>>1, half = tid&1;
    const uint4* src4 = reinterpret_cast<const uint4*>(&vT[d*72 + half*32]);
    uint4* dst4 = reinterpret_cast<uint4*>(vt + (size_t)b*SD*SN + (size_t)d*SN + nt*64 + half*32);
    dst4[0]=src4[0]; dst4[1]=src4[1]; dst4[2]=src4[2]; dst4[3]=src4[3];
  } else {
    // ---------------- q-block ----------------
    const unsigned short* WqT = wts;
    const float sc = 0.08838834764831845f;  // 1/sqrt(128)
    const float* xr = query + (rowbase + lm)*SD;
    bf16x8 af[4];
    for (int ks=0;ks<4;ks++){
      float4 x0 = *reinterpret_cast<const float4*>(xr + ks*32 + g*8);
      float4 x1 = *reinterpret_cast<const float4*>(xr + ks*32 + g*8 + 4);
      union { bf16x8 v; unsigned short s[8]; } u;
      u.s[0]=f2b(x0.x); u.s[1]=f2b(x0.y); u.s[2]=f2b(x0.z); u.s[3]=f2b(x0.w);
      u.s[4]=f2b(x1.x); u.s[5]=f2b(x1.y); u.s[6]=f2b(x1.z); u.s[7]=f2b(x1.w);
      af[ks]=u.v;
    }
    for (int d=0; d<8; d++){
      f32x4 acc = {0.f,0.f,0.f,0.f};
      for (int ks=0;ks<4;ks++){
        bf16x8 wf = *reinterpret_cast<const bf16x8*>(WqT + (d*16+lm)*SD + ks*32 + g*8);
        acc = __builtin_amdgcn_mfma_f32_16x16x32_bf16(af[ks], wf, acc, 0,0,0);
      }
      float bb = bq[d*16+lm];
      for (int r=0;r<4;r++)
        st[(4*g+r)*136 + d*16 + lm] = f2b((acc[r]+bb)*sc);
    }
    asm volatile("" ::: "memory");
    {
      const uint4* s4 = reinterpret_cast<const uint4*>(&st[srow*136 + sqtr*32]);
      uint4* d4 = reinterpret_cast<uint4*>(qb + (rowbase + srow)*SD + sqtr*32);
      d4[0]=s4[0]; d4[1]=s4[1]; d4[2]=s4[2]; d4[3]=s4[3];
    }
  }
}

// ---- flash attention + fused output projection ----
// Round-0 structure verbatim (the twice-measured 167us config): 512 blocks,
// 4 waves, 64 q-rows, 2 blocks/CU, natural block mapping, plain int mask
// loads with register prefetch. Only addition: TBAA fences on LDS strips.
__global__ __launch_bounds__(256,4) void flash_kernel(
    const unsigned short* __restrict__ qb, const unsigned short* __restrict__ kb,
    const unsigned short* __restrict__ vt, const int* __restrict__ mask,
    const unsigned short* __restrict__ WoT, const float* __restrict__ bo,
    float* __restrict__ out)
{
  __shared__ unsigned short bufK[2][64*128];   // [key][d], chunk-swizzled
  __shared__ unsigned short bufV[2][128*64];   // [d][key], chunk-swizzled
  __shared__ unsigned short ldsP[4*16*72];     // per-wave P strip

  int tid=threadIdx.x;
  int w=tid>>6, ln=tid&63, g=ln>>4, lm=ln&15;
  int b = blockIdx.x >> 5, qt = blockIdx.x & 31;
  int q0 = qt*64;

  const unsigned short* Qb = qb + (size_t)b*SN*SD;
  const unsigned short* Kb = kb + (size_t)b*SN*SD;
  const unsigned short* Vb = vt + (size_t)b*SD*SN;
  const int* Mb = mask + (size_t)b*NM*NM;

  auto issueK = [&](int k0, int bi){
    const char* gbase = (const char*)Kb + (size_t)k0*256;
    for (int c=0;c<4;c++){
      int p = c*256 + tid;
      int row = p>>4, lc = (p&15) ^ (row&15);
      async16(gbase + (size_t)row*256 + lc*16, (char*)bufK[bi] + p*16);
    }
  };
  auto issueV = [&](int k0, int bi){
    const char* gbase = (const char*)Vb + (size_t)k0*2;
    for (int c=0;c<4;c++){
      int p = c*256 + tid;
      int row = p>>3, lc = (p&7) ^ (row&7);
      async16(gbase + (size_t)row*4096 + lc*16, (char*)bufV[bi] + p*16);
    }
  };

  issueK(0,0); issueV(0,0);

  bf16x8 qf[4];
  {
    const unsigned short* qr = Qb + (size_t)(q0 + w*16 + lm)*SD;
    for (int ks=0;ks<4;ks++)
      qf[ks] = *reinterpret_cast<const bf16x8*>(qr + ks*32 + g*8);
  }

  int qr1 = 1 + q0 + w*16 + 4*g;
  const int* mbase = Mb + (size_t)qr1*NM + 1 + lm;
  int mreg[16];
  for (int ct=0;ct<4;ct++)
    for (int r=0;r<4;r++)
      mreg[ct*4+r] = mbase[(size_t)r*NM + ct*16];

  float mrow[4], lrow[4], al[4];
  f32x4 acc[8];
  for (int r=0;r<4;r++){ mrow[r]=-INFINITY; lrow[r]=0.f; }
  for (int d=0;d<8;d++){ f32x4 z={0.f,0.f,0.f,0.f}; acc[d]=z; }
  unsigned short* pw = &ldsP[w*16*72];

  for (int kt=0; kt<32; kt++){
    __syncthreads();          // DMA for buf[kt&1] drained; all done reading buf[(kt+1)&1]
    int cur = kt&1;
    if (kt<31){ issueK((kt+1)*64, cur^1); issueV((kt+1)*64, cur^1); }

    // ---- S = Q K^T (wave strip: 16 q-rows x 64 keys), swizzled reads ----
    f32x4 s[4];
    __builtin_amdgcn_s_setprio(1);
    for (int ct=0;ct<4;ct++){
      f32x4 z = {0.f,0.f,0.f,0.f};
      for (int ks=0;ks<4;ks++){
        bf16x8 kf = *reinterpret_cast<const bf16x8*>(
            &bufK[cur][(ct*16+lm)*128 + (((ks*4+g)^lm))*8]);
        z = __builtin_amdgcn_mfma_f32_16x16x32_bf16(qf[ks], kf, z, 0,0,0);
      }
      s[ct]=z;
    }
    __builtin_amdgcn_s_setprio(0);

    // apply inverted mask, then prefetch next tile's mask
    for (int ct=0;ct<4;ct++)
      for (int r=0;r<4;r++)
        s[ct][r] = mreg[ct*4+r] ? -INFINITY : s[ct][r];
    if (kt<31){
      const int* mp = mbase + (kt+1)*64;
      for (int ct=0;ct<4;ct++)
        for (int r=0;r<4;r++)
          mreg[ct*4+r] = mp[(size_t)r*NM + ct*16];
    }

    // ---- online softmax ----
    for (int r=0;r<4;r++){
      float v = fmaxf(fmaxf(s[0][r],s[1][r]), fmaxf(s[2][r],s[3][r]));
      v = fmaxf(v, __shfl_xor(v,1,16));
      v = fmaxf(v, __shfl_xor(v,2,16));
      v = fmaxf(v, __shfl_xor(v,4,16));
      v = fmaxf(v, __shfl_xor(v,8,16));
      float mn = fmaxf(mrow[r], v);
      bool dead = (mn == -INFINITY);    // fully-masked so far -> zeros (NaN->0 semantics)
      float a = dead ? 1.f : __expf(mrow[r]-mn);
      float rsum = 0.f;
      for (int ct=0;ct<4;ct++){
        float p = dead ? 0.f : __expf(s[ct][r]-mn);
        s[ct][r]=p; rsum += p;
      }
      rsum += __shfl_xor(rsum,1,16);
      rsum += __shfl_xor(rsum,2,16);
      rsum += __shfl_xor(rsum,4,16);
      rsum += __shfl_xor(rsum,8,16);
      lrow[r] = lrow[r]*a + rsum;
      mrow[r] = mn;
      al[r] = a;
    }
    for (int d=0;d<8;d++)
      for (int r=0;r<4;r++)
        acc[d][r] *= al[r];

    // P: C-layout -> per-wave LDS strip -> A-frags
    for (int ct=0;ct<4;ct++){
      int col = ct*16+lm;
      for (int r=0;r<4;r++)
        pw[(4*g+r)*72 + col] = f2b(s[ct][r]);
    }
    asm volatile("" ::: "memory");
    bf16x8 pa0 = *reinterpret_cast<const bf16x8*>(&pw[lm*72 + g*8]);
    bf16x8 pa1 = *reinterpret_cast<const bf16x8*>(&pw[lm*72 + 32 + g*8]);
    asm volatile("" ::: "memory");

    // O += P V (swizzled V reads)
    __builtin_amdgcn_s_setprio(1);
    for (int d=0;d<8;d++){
      bf16x8 v0 = *reinterpret_cast<const bf16x8*>(
          &bufV[cur][(d*16+lm)*64 + ((g^(lm&7)))*8]);
      acc[d] = __builtin_amdgcn_mfma_f32_16x16x32_bf16(pa0, v0, acc[d], 0,0,0);
      bf16x8 v1 = *reinterpret_cast<const bf16x8*>(
          &bufV[cur][(d*16+lm)*64 + (((4+g)^(lm&7)))*8]);
      acc[d] = __builtin_amdgcn_mfma_f32_16x16x32_bf16(pa1, v1, acc[d], 0,0,0);
    }
    __builtin_amdgcn_s_setprio(0);
  }

  // ---- epilogue: out = (O/l) @ Wo + bo ----
  __syncthreads();            // done with bufK/bufV; reuse as bf16 A-frag strips
  float inv[4];
  for (int r=0;r<4;r++) inv[r] = (lrow[r] > 0.f) ? (1.f/lrow[r]) : 0.f;
  unsigned short* strip = &bufK[0][0] + w*2176;   // 16 rows x 136 stride
  for (int d=0;d<8;d++)
    for (int r=0;r<4;r++)
      strip[(4*g+r)*136 + d*16 + lm] = f2b(acc[d][r]*inv[r]);
  asm volatile("" ::: "memory");
  bf16x8 oa[4];
  for (int ks=0;ks<4;ks++)
    oa[ks] = *reinterpret_cast<const bf16x8*>(&strip[lm*136 + ks*32 + g*8]);
  asm volatile("" ::: "memory");
  float* Ob = out + ((size_t)b*SN + q0 + w*16)*SD;
  for (int dc=0; dc<8; dc++){
    f32x4 o = {0.f,0.f,0.f,0.f};
    for (int ks=0;ks<4;ks++){
      bf16x8 wf = *reinterpret_cast<const bf16x8*>(WoT + (dc*16+lm)*SD + ks*32 + g*8);
      o = __builtin_amdgcn_mfma_f32_16x16x32_bf16(oa[ks], wf, o, 0,0,0);
    }
    float bb = bo[dc*16+lm];
    for (int r=0;r<4;r++)
      Ob[(size_t)(4*g+r)*SD + dc*16 + lm] = o[r]+bb;
  }
}

extern "C" void kernel_launch(void* const* d_in, const int* in_sizes, int n_in,
                              void* d_out, int out_size, void* d_ws, size_t ws_size,
                              hipStream_t stream)
{
  const float* query = (const float*)d_in[0];
  const float* key   = (const float*)d_in[1];
  const int*   mask  = (const int*)d_in[2];
  const float* Wq = (const float*)d_in[3];
  const float* bq = (const float*)d_in[4];
  const float* Wk = (const float*)d_in[5];
  const float* bk = (const float*)d_in[6];
  const float* Wv = (const float*)d_in[7];
  const float* bv = (const float*)d_in[8];
  const float* Wo = (const float*)d_in[9];
  const float* bo = (const float*)d_in[10];
  float* out = (float*)d_out;

  // workspace: qb, kb, vt (bf16) + transposed weights + fused bias
  unsigned short* qb = (unsigned short*)d_ws;
  unsigned short* kb = qb + SZ;
  unsigned short* vt = kb + SZ;
  unsigned short* wts = vt + SZ;            // WqT | WkT | WkvT(overwrites WvT) | WoT
  float* bkv = (float*)(wts + 65536);       // 128 f32

  prep_w_kernel  <<<64,256,0,stream>>>(Wq,Wk,Wv,Wo,wts);
  prep_wkv_kernel<<<16,256,0,stream>>>(Wk,Wv,bk,bv, wts+32768, bkv);
  qkv_kernel     <<<1024,256,0,stream>>>(query, key, wts, bq, bk, bkv, qb, kb, vt);
  flash_kernel   <<<512,256,0,stream>>>(qb, kb, vt, mask, wts+49152, bo, out);
}